// Round 11
// baseline (226.585 us; speedup 1.0000x reference)
//
#include <hip/hip_runtime.h>

// CIN (xDeepFM) — fused split-bf16 MFMA v5 for MI355X (gfx950).
//
// out[b,s,d] = relu( sum_{f,g} x[b,f,d]*h[b,g,d]*W[f*64+g, s] + b[s] )
// Rows m=(b,d) independent across the 3-layer chain -> one fused kernel,
// h lives in LDS between layers (v4-validated). K = 2496 = 39 f-groups x 64.
//
// v5 vs v4 (round 9: 153us, Occupancy 11% = 1 wave/SIMD, latency-bound):
//  - 8 waves/block (512 thr), COLUMN-SPLIT: wave (wr,cg) owns rows wr*32..+31
//    and cols cg*64..+63 (2 cf, acc[2], 8 B-reads/iter). 2 waves/SIMD ->
//    one wave's VALU A-build overlaps the other's MFMA phase.
//  - Same triple-buffered stage ledger as v4, per-wave quota 4->2 loads:
//    vmcnt(4) -> vmcnt(2). Prologue/steady/epilogue states identical.
//  - s_setprio(1) around MFMA bursts (T5: pays only with role-split waves,
//    which this structure now has).
//  - A-build duplicated between cg-pair waves (accepted; K-split dedup is
//    the next lever if VALU-bound confirms).
//
// Round-10 note: GPU never acquired; v5 re-audited (2-load vmcnt ledger,
// stage coverage, column-split epilogue coverage, cross-layer WAR, VGPR/LDS
// budget) and resubmitted unchanged (one dead typedef removed).

typedef __bf16 bf16x8 __attribute__((ext_vector_type(8)));
typedef float  f32x16 __attribute__((ext_vector_type(16)));

#define NF    39
#define PACKN 319488         // 2496*128 packed ushort per layer
#define PACKB 1248           // pack blocks per layer (1248*256 == PACKN)

// ---- prep: pack all 3 W (fp32 [K][128]) -> bf16-hi fragment order ----
// ushort idx = ((step16*4 + cf)*64 + lane)*8 + j ; k = step16*16+(lane>>5)*8+j ;
// s = cf*32+(lane&31).  f-group f = uint4 range [f*1024,(f+1)*1024).
__global__ void pack_w_all(const float* __restrict__ W0,
                           const float* __restrict__ W1,
                           const float* __restrict__ W2,
                           unsigned short* __restrict__ dst) {
    int bid   = blockIdx.x;
    int layer = bid / PACKB;
    int idx   = (bid - layer * PACKB) * 256 + threadIdx.x;   // < PACKN exactly
    int j    = idx & 7;
    int lane = (idx >> 3) & 63;
    int cf   = (idx >> 9) & 3;
    int step = idx >> 11;
    int k = step * 16 + (lane >> 5) * 8 + j;
    int s = cf * 32 + (lane & 31);
    float v;
    if (layer == 0) {
        int f = k >> 6, g = k & 63;
        v = (g < 39) ? W0[(f * 39 + g) * 128 + s] : 0.f;
    } else if (layer == 1) {
        v = W1[k * 128 + s];
    } else {
        v = W2[k * 128 + s];
    }
    __bf16 h = (__bf16)v;
    dst[layer * PACKN + idx] = __builtin_bit_cast(unsigned short, h);
}

// ---- fused 3-layer CIN, 8 waves ----
__launch_bounds__(512, 2)
__global__ void cin_fused(const float* __restrict__ xg,
                          const uint4* __restrict__ Wp,     // 3 x 39936 uint4
                          const float* __restrict__ b0g,
                          const float* __restrict__ b1g,
                          const float* __restrict__ b2g,
                          float* __restrict__ outg) {
    __shared__ __attribute__((aligned(16))) float xs[128][41];  // 21 KB
    __shared__ __attribute__((aligned(16))) float hs[128][68];  // 35 KB
    __shared__ uint4 WL[3][1024];                               // 48 KB

    const int tid = threadIdx.x;
    const int w   = tid >> 6;           // wave 0..7
    const int l   = tid & 63;
    const int wr  = w >> 1;             // row group: rows wr*32..+31
    const int cg  = w & 1;              // col group: cols cg*64..+63
    const int m0  = blockIdx.x * 128;   // first (b,d) row; b=m>>4, d=m&15
    const int b0  = m0 >> 4;            // 8 batch elems per block

    // ---- stage x rows once: xs[bl*16+d][f] = x[b0+bl, f, d] ----
    for (int idx = tid; idx < 8 * 39 * 16; idx += 512) {
        int bl_ = idx / 624, rem = idx - bl_ * 624;
        int f = rem >> 4, d = rem & 15;
        xs[bl_ * 16 + d][f] = xg[(((b0 + bl_) * 39 + f) << 4) + d];
    }

    const int r    = l & 31;            // A row in tile / C col
    const int hb   = l >> 5;            // k-half select
    const int hrow = wr * 32 + r;
    const int b_base = b0 + wr * 2;

    #pragma unroll
    for (int layer = 0; layer < 3; ++layer) {
        const uint4* WB = Wp + layer * (PACKN / 8);
        const float* bp = (layer == 0) ? b0g : ((layer == 1) ? b1g : b2g);

        // ---- staging: one K64 f-group -> WL[slot]; 2 loads/wave ----
        auto stage = [&](int f, int slot) {
            #pragma unroll
            for (int i = 0; i < 2; ++i)
                __builtin_amdgcn_global_load_lds(
                    (const unsigned int*)(WB + f * 1024 + (w * 2 + i) * 64 + l),
                    (unsigned int*)&WL[slot][(w * 2 + i) * 64], 16, 0, 0);
        };

        stage(0, 0);
        stage(1, 1);
        __syncthreads();    // full drain; publishes prev-layer hs / xs

        // ---- hoist this lane's h row (g = sub*16 + hb*8 + jj) ----
        float hr[4][8];
        if (layer == 0) {
            #pragma unroll
            for (int sub = 0; sub < 4; ++sub)
                #pragma unroll
                for (int jj = 0; jj < 8; ++jj) {
                    int g = sub * 16 + hb * 8 + jj;
                    hr[sub][jj] = (g < 39) ? xs[hrow][g] : 0.f;
                }
        } else {
            #pragma unroll
            for (int sub = 0; sub < 4; ++sub) {
                float4 a = *reinterpret_cast<const float4*>(&hs[hrow][sub * 16 + hb * 8]);
                float4 bq = *reinterpret_cast<const float4*>(&hs[hrow][sub * 16 + hb * 8 + 4]);
                hr[sub][0] = a.x;  hr[sub][1] = a.y;  hr[sub][2] = a.z;  hr[sub][3] = a.w;
                hr[sub][4] = bq.x; hr[sub][5] = bq.y; hr[sub][6] = bq.z; hr[sub][7] = bq.w;
            }
        }

        f32x16 acc[2];
        #pragma unroll
        for (int c = 0; c < 2; ++c)
            #pragma unroll
            for (int i = 0; i < 16; ++i) acc[c][i] = 0.f;

        // ---- body: one f-group; wave covers its 2 col-frags ----
        auto body = [&](int f, const uint4* WLb) {
            uint4 B[8];
            #pragma unroll
            for (int sub = 0; sub < 4; ++sub)
                #pragma unroll
                for (int j = 0; j < 2; ++j)
                    B[sub * 2 + j] = WLb[(sub * 4 + cg * 2 + j) * 64 + l];
            float xv = xs[hrow][f];
            bf16x8 ah[4], al[4];
            #pragma unroll
            for (int sub = 0; sub < 4; ++sub)
                #pragma unroll
                for (int jj = 0; jj < 8; ++jj) {
                    float p = xv * hr[sub][jj];
                    __bf16 ph = (__bf16)p;
                    ah[sub][jj] = ph;
                    al[sub][jj] = (__bf16)(p - (float)ph);
                }
            __builtin_amdgcn_s_setprio(1);
            #pragma unroll
            for (int sub = 0; sub < 4; ++sub)
                #pragma unroll
                for (int j = 0; j < 2; ++j)
                    acc[j] = __builtin_amdgcn_mfma_f32_32x32x16_bf16(
                        ah[sub], __builtin_bit_cast(bf16x8, B[sub * 2 + j]), acc[j], 0, 0, 0);
            #pragma unroll
            for (int sub = 0; sub < 4; ++sub)
                #pragma unroll
                for (int j = 0; j < 2; ++j)
                    acc[j] = __builtin_amdgcn_mfma_f32_32x32x16_bf16(
                        al[sub], __builtin_bit_cast(bf16x8, B[sub * 2 + j]), acc[j], 0, 0, 0);
            __builtin_amdgcn_s_setprio(0);
        };

        // ---- K loop: vmcnt(2) retires own stage(f); barrier publishes ----
        int slot = 0;
        for (int f = 0; f < NF - 1; ++f) {
            asm volatile("s_waitcnt vmcnt(2)" ::: "memory");
            __builtin_amdgcn_s_barrier();
            __builtin_amdgcn_sched_barrier(0);
            if (f <= NF - 3) stage(f + 2, slot >= 1 ? slot - 1 : slot + 2);
            body(f, WL[slot]);
            slot = (slot == 2) ? 0 : slot + 1;
        }
        asm volatile("s_waitcnt vmcnt(0)" ::: "memory");
        __builtin_amdgcn_s_barrier();
        __builtin_amdgcn_sched_barrier(0);
        body(NF - 1, WL[slot]);

        // ---- epilogue: bias+relu; h-part -> hs (LDS); direct -> d_out ----
        // C/D 32x32 map (m74/m101): col=lane&31, row=(reg&3)+8*(reg>>2)+4*(lane>>5)
        #pragma unroll
        for (int cf2 = 0; cf2 < 2; ++cf2) {
            int s = (cg * 2 + cf2) * 32 + r;
            float bias = bp[s];
            float v[16], s0 = 0.f, s1 = 0.f;
            #pragma unroll
            for (int reg = 0; reg < 16; ++reg) {
                float vv = fmaxf(acc[cf2][reg] + bias, 0.f);
                v[reg] = vv;
                if (reg < 8) s0 += vv; else s1 += vv;
            }
            if (layer < 2 && s < 64) {          // cg==0 waves cover cols 0..63
                #pragma unroll
                for (int reg = 0; reg < 16; ++reg) {
                    int trow = (reg & 3) + 8 * (reg >> 2) + 4 * hb;
                    hs[wr * 32 + trow][s] = v[reg];
                }
            }
            s0 += __shfl_xor(s0, 32, 64);       // join d-halves across hb groups
            s1 += __shfl_xor(s1, 32, 64);
            int col = (layer == 0) ? (s - 64) : ((layer == 1) ? s : s + 128);
            bool direct = (layer == 2) || (s >= 64);
            if (direct && l < 32) {
                outg[b_base * 256 + col]       = s0;
                outg[(b_base + 1) * 256 + col] = s1;
            }
        }
        // Next layer: stage(0/1) reuse WL[0]/WL[1] (last read f=36/37, retired
        // before the f=38 barrier all waves crossed); hs read only after the
        // next layer's __syncthreads. No hazards.
    }
}

extern "C" void kernel_launch(void* const* d_in, const int* in_sizes, int n_in,
                              void* d_out, int out_size, void* d_ws, size_t ws_size,
                              hipStream_t stream) {
    const float* x  = (const float*)d_in[0];
    const float* W0 = (const float*)d_in[1];
    const float* W1 = (const float*)d_in[2];
    const float* W2 = (const float*)d_in[3];
    const float* b0 = (const float*)d_in[4];
    const float* b1 = (const float*)d_in[5];
    const float* b2 = (const float*)d_in[6];
    float* out = (float*)d_out;

    unsigned short* Wpk = (unsigned short*)d_ws;     // 3 x PACKN ushort = 1.92 MB

    pack_w_all<<<dim3(3 * PACKB), dim3(256), 0, stream>>>(W0, W1, W2, Wpk);
    cin_fused<<<dim3(256), dim3(512), 0, stream>>>(
        x, (const uint4*)Wpk, b0, b1, b2, out);
}

// Round 13
// 200.339 us; speedup vs baseline: 1.1310x; 1.1310x over previous
//
#include <hip/hip_runtime.h>

// CIN (xDeepFM) — fused split-bf16 MFMA v6.1 for MI355X (gfx950).
//
// out[b,s,d] = relu( sum_{f,g} x[b,f,d]*h[b,g,d]*W[f*64+g, s] + b[s] )
// Rows m=(b,d) independent across the 3-layer chain -> one fused kernel,
// h lives in LDS between layers. K = 2496 = 39 f-groups x 64.
//
// v6 = v4 (round 9: 153us) + prefetch depth 2 -> 5. Evidence: per-iter time
// tracks L_mem/depth (v2 0.9us @ depth1, v4 1.31us @ depth2, work sums to
// ~600cyc) -> W-stream latency ~2500-3000cyc is the binder, not any pipe.
// v5's 8-wave TLP attempt regressed (176us): barrier-lockstep waves share
// phase, so TLP can't hide latency here; pipeline depth must.
//  - WL[3] -> WL[6] slots (LDS 150.5KB, 1 block/CU, 4 waves).
//  - steady vmcnt(16) (5 stages x 4 loads in flight, retire own stage(f));
//    tail 16/12/8/4/0. Prologue stages 0..4 + full-drain sync.
//  - no setprio; acc[4], B[16] hoist, 4 indep MFMA chains (v4 body).
// v6.1 (round-12 audit fix): end-of-layer __syncthreads. v6 had a WAR race:
// body(38) reads WL[2] AFTER the last K-loop barrier, while a fast wave's
// next-layer prologue re-stages WL[0..4] (incl. 2) with no barrier between.
// v4 was safe only because its depth-2 prologue rewrote slots {0,1}, whose
// last reads were barrier-separated; depth-5 widened the overwrite set.

typedef __bf16 bf16x8 __attribute__((ext_vector_type(8)));
typedef float  f32x16 __attribute__((ext_vector_type(16)));

#define NF    39
#define PACKN 319488         // 2496*128 packed ushort per layer
#define PACKB 1248           // pack blocks per layer (1248*256 == PACKN)

// ---- prep: pack all 3 W (fp32 [K][128]) -> bf16-hi fragment order ----
// ushort idx = ((step16*4 + cf)*64 + lane)*8 + j ; k = step16*16+(lane>>5)*8+j ;
// s = cf*32+(lane&31).  f-group f = uint4 range [f*1024,(f+1)*1024).
__global__ void pack_w_all(const float* __restrict__ W0,
                           const float* __restrict__ W1,
                           const float* __restrict__ W2,
                           unsigned short* __restrict__ dst) {
    int bid   = blockIdx.x;
    int layer = bid / PACKB;
    int idx   = (bid - layer * PACKB) * 256 + threadIdx.x;   // < PACKN exactly
    int j    = idx & 7;
    int lane = (idx >> 3) & 63;
    int cf   = (idx >> 9) & 3;
    int step = idx >> 11;
    int k = step * 16 + (lane >> 5) * 8 + j;
    int s = cf * 32 + (lane & 31);
    float v;
    if (layer == 0) {
        int f = k >> 6, g = k & 63;
        v = (g < 39) ? W0[(f * 39 + g) * 128 + s] : 0.f;
    } else if (layer == 1) {
        v = W1[k * 128 + s];
    } else {
        v = W2[k * 128 + s];
    }
    __bf16 h = (__bf16)v;
    dst[layer * PACKN + idx] = __builtin_bit_cast(unsigned short, h);
}

// ---- fused 3-layer CIN, 4 waves, depth-5 W pipeline ----
__launch_bounds__(256, 1)
__global__ void cin_fused(const float* __restrict__ xg,
                          const uint4* __restrict__ Wp,     // 3 x 39936 uint4
                          const float* __restrict__ b0g,
                          const float* __restrict__ b1g,
                          const float* __restrict__ b2g,
                          float* __restrict__ outg) {
    __shared__ __attribute__((aligned(16))) float xs[128][41];  // 21.0 KB
    __shared__ __attribute__((aligned(16))) float hs[128][68];  // 34.8 KB
    __shared__ uint4 WL[6][1024];                               // 96 KB: 6 slots

    const int tid = threadIdx.x;
    const int w   = tid >> 6;           // wave 0..3 -> rows w*32..w*32+31
    const int l   = tid & 63;
    const int m0  = blockIdx.x * 128;   // first (b,d) row; b=m>>4, d=m&15
    const int b0  = m0 >> 4;            // 8 batch elems per block

    // ---- stage x rows once: xs[bl*16+d][f] = x[b0+bl, f, d] ----
    for (int idx = tid; idx < 8 * 39 * 16; idx += 256) {
        int bl_ = idx / 624, rem = idx - bl_ * 624;
        int f = rem >> 4, d = rem & 15;
        xs[bl_ * 16 + d][f] = xg[(((b0 + bl_) * 39 + f) << 4) + d];
    }

    const int r    = l & 31;            // A row in tile / C col
    const int hb   = l >> 5;            // k-half select
    const int hrow = w * 32 + r;
    const int b_base = b0 + w * 2;

    #pragma unroll
    for (int layer = 0; layer < 3; ++layer) {
        const uint4* WB = Wp + layer * (PACKN / 8);
        const float* bp = (layer == 0) ? b0g : ((layer == 1) ? b1g : b2g);

        // ---- staging helper: one K64 f-group -> WL[slot]; 4 loads/wave ----
        auto stage = [&](int f, int slot) {
            #pragma unroll
            for (int i = 0; i < 4; ++i)
                __builtin_amdgcn_global_load_lds(
                    (const unsigned int*)(WB + f * 1024 + i * 256 + w * 64 + l),
                    (unsigned int*)&WL[slot][i * 256 + w * 64], 16, 0, 0);
        };

        // ---- prologue: fill 5 slots, full drain ----
        stage(0, 0); stage(1, 1); stage(2, 2); stage(3, 3); stage(4, 4);
        __syncthreads();    // drains stages 0-4; publishes prev-layer hs / xs

        // ---- hoist this lane's h row (g = sub*16 + hb*8 + jj) ----
        float hr[4][8];
        if (layer == 0) {
            #pragma unroll
            for (int sub = 0; sub < 4; ++sub)
                #pragma unroll
                for (int jj = 0; jj < 8; ++jj) {
                    int g = sub * 16 + hb * 8 + jj;
                    hr[sub][jj] = (g < 39) ? xs[hrow][g] : 0.f;
                }
        } else {
            #pragma unroll
            for (int sub = 0; sub < 4; ++sub) {
                float4 a = *reinterpret_cast<const float4*>(&hs[hrow][sub * 16 + hb * 8]);
                float4 bq = *reinterpret_cast<const float4*>(&hs[hrow][sub * 16 + hb * 8 + 4]);
                hr[sub][0] = a.x;  hr[sub][1] = a.y;  hr[sub][2] = a.z;  hr[sub][3] = a.w;
                hr[sub][4] = bq.x; hr[sub][5] = bq.y; hr[sub][6] = bq.z; hr[sub][7] = bq.w;
            }
        }

        f32x16 acc[4];
        #pragma unroll
        for (int c = 0; c < 4; ++c)
            #pragma unroll
            for (int i = 0; i < 16; ++i) acc[c][i] = 0.f;

        // ---- body: one f-group; B in regs, A-builds first, 4 indep chains ----
        auto body = [&](int f, const uint4* WLb) {
            uint4 B[16];
            #pragma unroll
            for (int i = 0; i < 16; ++i) B[i] = WLb[i * 64 + l];
            float xv = xs[hrow][f];
            bf16x8 ah[4], al[4];
            #pragma unroll
            for (int sub = 0; sub < 4; ++sub)
                #pragma unroll
                for (int jj = 0; jj < 8; ++jj) {
                    float p = xv * hr[sub][jj];
                    __bf16 ph = (__bf16)p;
                    ah[sub][jj] = ph;
                    al[sub][jj] = (__bf16)(p - (float)ph);
                }
            #pragma unroll
            for (int sub = 0; sub < 4; ++sub)
                #pragma unroll
                for (int cf = 0; cf < 4; ++cf)
                    acc[cf] = __builtin_amdgcn_mfma_f32_32x32x16_bf16(
                        ah[sub], __builtin_bit_cast(bf16x8, B[sub * 4 + cf]), acc[cf], 0, 0, 0);
            #pragma unroll
            for (int sub = 0; sub < 4; ++sub)
                #pragma unroll
                for (int cf = 0; cf < 4; ++cf)
                    acc[cf] = __builtin_amdgcn_mfma_f32_32x32x16_bf16(
                        al[sub], __builtin_bit_cast(bf16x8, B[sub * 4 + cf]), acc[cf], 0, 0, 0);
        };

        // ---- K loop, depth-5: retire own stage(f), issue stage(f+5) ----
        // steady: 5 stages x 4 loads in flight -> vmcnt(16); tail 16/12/8/4/0.
        int slot = 0;                        // f % 6
        int pslot = 5;                       // (f+5) % 6
        for (int f = 0; f < NF; ++f) {
            if (f <= NF - 5)      asm volatile("s_waitcnt vmcnt(16)" ::: "memory");
            else if (f == NF - 4) asm volatile("s_waitcnt vmcnt(12)" ::: "memory");
            else if (f == NF - 3) asm volatile("s_waitcnt vmcnt(8)"  ::: "memory");
            else if (f == NF - 2) asm volatile("s_waitcnt vmcnt(4)"  ::: "memory");
            else                  asm volatile("s_waitcnt vmcnt(0)"  ::: "memory");
            __builtin_amdgcn_s_barrier();
            __builtin_amdgcn_sched_barrier(0);
            if (f + 5 < NF) stage(f + 5, pslot);
            body(f, WL[slot]);
            slot  = (slot  == 5) ? 0 : slot + 1;
            pslot = (pslot == 5) ? 0 : pslot + 1;
        }

        // ---- epilogue: bias+relu; h-part -> hs (LDS); direct -> d_out ----
        // C/D 32x32 map (m74/m101): col=lane&31, row=(reg&3)+8*(reg>>2)+4*(lane>>5)
        #pragma unroll
        for (int cf = 0; cf < 4; ++cf) {
            int s = cf * 32 + r;
            float bias = bp[s];
            float v[16], s0 = 0.f, s1 = 0.f;
            #pragma unroll
            for (int reg = 0; reg < 16; ++reg) {
                float vv = fmaxf(acc[cf][reg] + bias, 0.f);
                v[reg] = vv;
                if (reg < 8) s0 += vv; else s1 += vv;
            }
            if (layer < 2 && s < 64) {
                #pragma unroll
                for (int reg = 0; reg < 16; ++reg) {
                    int trow = (reg & 3) + 8 * (reg >> 2) + 4 * hb;
                    hs[w * 32 + trow][s] = v[reg];
                }
            }
            s0 += __shfl_xor(s0, 32, 64);   // join d-halves across hb groups
            s1 += __shfl_xor(s1, 32, 64);
            int col = (layer == 0) ? (s - 64) : ((layer == 1) ? s : s + 128);
            bool direct = (layer == 2) || (s >= 64);
            if (direct && l < 32) {
                outg[b_base * 256 + col]       = s0;
                outg[(b_base + 1) * 256 + col] = s1;
            }
        }
        // v6.1 race fix: publish body(38)'s WL reads (slot 2, post-barrier)
        // and this epilogue's hs writes BEFORE any wave issues the next
        // layer's prologue stage writes into WL[0..4].
        __syncthreads();
    }
}

extern "C" void kernel_launch(void* const* d_in, const int* in_sizes, int n_in,
                              void* d_out, int out_size, void* d_ws, size_t ws_size,
                              hipStream_t stream) {
    const float* x  = (const float*)d_in[0];
    const float* W0 = (const float*)d_in[1];
    const float* W1 = (const float*)d_in[2];
    const float* W2 = (const float*)d_in[3];
    const float* b0 = (const float*)d_in[4];
    const float* b1 = (const float*)d_in[5];
    const float* b2 = (const float*)d_in[6];
    float* out = (float*)d_out;

    unsigned short* Wpk = (unsigned short*)d_ws;     // 3 x PACKN ushort = 1.92 MB

    pack_w_all<<<dim3(3 * PACKB), dim3(256), 0, stream>>>(W0, W1, W2, Wpk);
    cin_fused<<<dim3(256), dim3(256), 0, stream>>>(
        x, (const uint4*)Wpk, b0, b1, b2, out);
}